// Round 3
// baseline (371.903 us; speedup 1.0000x reference)
//
#include <hip/hip_runtime.h>
#include <math.h>

#define BN 256
#define SN 196
#define RN 1024
#define HN 512
#define KSPLIT 8
#define KCH 128   // per gemm block: two 64-wide sub-chunks, LDS reused
#define SSPLIT 8  // scores s-splits
#define PSPLIT 8  // pool s-splits

__device__ __forceinline__ float fast_tanh(float x) {
    // tanh(x) = 1 - 2/(exp(2x)+1); exact saturation at +/-inf
    float e = __expf(2.0f * x);
    return 1.0f - 2.0f * __builtin_amdgcn_rcpf(e + 1.0f);
}

// ---------------- kernel 1: split-K GEMV partials (proven ~10us) ----------------
// partial[kc][b][h] = hidden[b, kc*128:(kc+1)*128] . w[h, kc*128:(kc+1)*128]
__global__ __launch_bounds__(256) void k_gemm_partial(
    const float* __restrict__ hidden, const float* __restrict__ w,
    float* __restrict__ partial) {
    __shared__ float At[64][64];
    __shared__ float Bt[64][64];
    const int t  = threadIdx.x;
    const int b0 = blockIdx.x * 64;
    const int h0 = blockIdx.y * 64;
    const int kc = blockIdx.z;

    const int th4 = (t & 15) * 4;
    const int tb4 = (t >> 4) * 4;
    float4 acc0 = {0,0,0,0}, acc1 = {0,0,0,0}, acc2 = {0,0,0,0}, acc3 = {0,0,0,0};

    for (int sub = 0; sub < 2; ++sub) {
        const int k0 = kc * KCH + sub * 64;
        {
            const int row = t >> 2, kq = (t & 3) * 16;
            const float* srcA = hidden + (size_t)(b0 + row) * RN + k0 + kq;
            const float* srcB = w      + (size_t)(h0 + row) * RN + k0 + kq;
#pragma unroll
            for (int j = 0; j < 4; ++j) {
                float4 v = *(const float4*)(srcA + j * 4);
                int k = kq + j * 4;
                At[k][row] = v.x; At[k+1][row] = v.y; At[k+2][row] = v.z; At[k+3][row] = v.w;
            }
#pragma unroll
            for (int j = 0; j < 4; ++j) {
                float4 v = *(const float4*)(srcB + j * 4);
                int k = kq + j * 4;
                Bt[k][row] = v.x; Bt[k+1][row] = v.y; Bt[k+2][row] = v.z; Bt[k+3][row] = v.w;
            }
        }
        __syncthreads();
#pragma unroll 8
        for (int k = 0; k < 64; ++k) {
            float4 a  = *(const float4*)&At[k][tb4];
            float4 bb = *(const float4*)&Bt[k][th4];
            acc0.x = fmaf(a.x, bb.x, acc0.x); acc0.y = fmaf(a.x, bb.y, acc0.y);
            acc0.z = fmaf(a.x, bb.z, acc0.z); acc0.w = fmaf(a.x, bb.w, acc0.w);
            acc1.x = fmaf(a.y, bb.x, acc1.x); acc1.y = fmaf(a.y, bb.y, acc1.y);
            acc1.z = fmaf(a.y, bb.z, acc1.z); acc1.w = fmaf(a.y, bb.w, acc1.w);
            acc2.x = fmaf(a.z, bb.x, acc2.x); acc2.y = fmaf(a.z, bb.y, acc2.y);
            acc2.z = fmaf(a.z, bb.z, acc2.z); acc2.w = fmaf(a.z, bb.w, acc2.w);
            acc3.x = fmaf(a.w, bb.x, acc3.x); acc3.y = fmaf(a.w, bb.y, acc3.y);
            acc3.z = fmaf(a.w, bb.z, acc3.z); acc3.w = fmaf(a.w, bb.w, acc3.w);
        }
        __syncthreads();
    }
    float* dst = partial + ((size_t)kc * BN + b0 + tb4) * HN + h0 + th4;
    *(float4*)(dst)          = acc0;
    *(float4*)(dst + HN)     = acc1;
    *(float4*)(dst + 2 * HN) = acc2;
    *(float4*)(dst + 3 * HN) = acc3;
}

// ---------------- kernel 2: raw scores, 8-way s-split, 100% occupancy ----------------
// grid (BN, SSPLIT) x 256 thr -> 8 blocks/CU x 4 waves = 32 waves/CU.
// Per block: fold split-K partial reduce (redundant per sq, L2-mostly),
// then each wave computes its score rows (2 per iter for ILP). Raw scores out.
__global__ __launch_bounds__(256) void k_scores(
    const float* __restrict__ partial, const float* __restrict__ bias,
    const float* __restrict__ p_att, const float* __restrict__ in_w,
    const float* __restrict__ alpha_w, float* __restrict__ sc_out) {
    __shared__ float att_h[HN];
    __shared__ float wsm[32];
    const int b    = blockIdx.x;
    const int sq   = blockIdx.y;
    const int t    = threadIdx.x;
    const int wv   = t >> 6;
    const int lane = t & 63;
    const int base = sq * 24 + (sq < 4 ? sq : 4);   // 25,25,25,25,24,24,24,24
    const int cnt  = 24 + (sq < 4 ? 1 : 0);

    // att_h[h] = bias[h] + sum_kc partial[kc][b][h]
    if (t < 128) {
        float4 s = *(const float4*)(bias + t * 4);
        const float* p = partial + (size_t)b * HN + t * 4;
#pragma unroll
        for (int kc = 0; kc < KSPLIT; ++kc) {
            float4 v = *(const float4*)(p + (size_t)kc * BN * HN);
            s.x += v.x; s.y += v.y; s.z += v.z; s.w += v.w;
        }
        *(float4*)&att_h[t * 4] = s;
    }
    if (t < cnt) wsm[t] = in_w[b * SN + base + t];
    __syncthreads();

    const float4* a4 = (const float4*)alpha_w;
    const float4 aw0 = a4[lane], aw1 = a4[lane + 64];
    const float4 ah0 = *(const float4*)&att_h[lane * 4];
    const float4 ah1 = *(const float4*)&att_h[(lane + 64) * 4];
    const float4* p4 = (const float4*)p_att;
    // wave wv: row pairs (wv, wv+4), (wv+8, wv+12), ... within [0,cnt)
    for (int i = wv; i < cnt; i += 8) {
        const int  j  = i + 4;
        const bool h2 = (j < cnt);
        const float iw0 = wsm[i];
        const float iw1 = h2 ? wsm[j] : 0.0f;
        const size_t r0 = (size_t)(b * SN + base + i) * (HN / 4);
        const size_t r1 = (size_t)(b * SN + base + (h2 ? j : i)) * (HN / 4);
        float4 x00 = p4[r0 + lane], x01 = p4[r0 + lane + 64];
        float4 x10 = p4[r1 + lane], x11 = p4[r1 + lane + 64];
        float s0, s1;
        s0  = fast_tanh(fmaf(iw0, x00.x, ah0.x)) * aw0.x;
        s1  = fast_tanh(fmaf(iw1, x10.x, ah0.x)) * aw0.x;
        s0 += fast_tanh(fmaf(iw0, x00.y, ah0.y)) * aw0.y;
        s1 += fast_tanh(fmaf(iw1, x10.y, ah0.y)) * aw0.y;
        s0 += fast_tanh(fmaf(iw0, x00.z, ah0.z)) * aw0.z;
        s1 += fast_tanh(fmaf(iw1, x10.z, ah0.z)) * aw0.z;
        s0 += fast_tanh(fmaf(iw0, x00.w, ah0.w)) * aw0.w;
        s1 += fast_tanh(fmaf(iw1, x10.w, ah0.w)) * aw0.w;
        s0 += fast_tanh(fmaf(iw0, x01.x, ah1.x)) * aw1.x;
        s1 += fast_tanh(fmaf(iw1, x11.x, ah1.x)) * aw1.x;
        s0 += fast_tanh(fmaf(iw0, x01.y, ah1.y)) * aw1.y;
        s1 += fast_tanh(fmaf(iw1, x11.y, ah1.y)) * aw1.y;
        s0 += fast_tanh(fmaf(iw0, x01.z, ah1.z)) * aw1.z;
        s1 += fast_tanh(fmaf(iw1, x11.z, ah1.z)) * aw1.z;
        s0 += fast_tanh(fmaf(iw0, x01.w, ah1.w)) * aw1.w;
        s1 += fast_tanh(fmaf(iw1, x11.w, ah1.w)) * aw1.w;
#pragma unroll
        for (int off = 32; off; off >>= 1) {
            s0 += __shfl_xor(s0, off, 64);
            s1 += __shfl_xor(s1, off, 64);
        }
        if (lane == 0) {
            sc_out[b * SN + base + i] = s0;
            if (h2) sc_out[b * SN + base + j] = s1;
        }
    }
}

// ---------------- kernel 3: redundant softmax + pool partials ----------------
// grid (BN, PSPLIT) x 256 thr = 32 waves/CU. Each block recomputes softmax
// from the 196 raw scores (bitwise-identical across blocks -> deterministic);
// sq==0 writes weight_out. Then pools its 24-25 s rows over its r-quarter.
__global__ __launch_bounds__(256) void k_pool(
    const float* __restrict__ sc_in, const float* __restrict__ att_feats,
    float* __restrict__ pool_part, float* __restrict__ weight_out) {
    __shared__ float sc[256];
    __shared__ float wred[8];
    const int b  = blockIdx.x, sq = blockIdx.y;
    const int t  = threadIdx.x, q = t >> 6, lane = t & 63;

    // softmax over 196 (all 256 threads; t>=SN contribute -inf/0)
    float v = (t < SN) ? sc_in[b * SN + t] : -1e30f;
    float m = v;
#pragma unroll
    for (int off = 32; off; off >>= 1) m = fmaxf(m, __shfl_xor(m, off, 64));
    if (lane == 0) wred[q] = m;
    __syncthreads();
    m = fmaxf(fmaxf(wred[0], wred[1]), fmaxf(wred[2], wred[3]));
    float e = (t < SN) ? __expf(v - m) : 0.0f;
    float s = e;
#pragma unroll
    for (int off = 32; off; off >>= 1) s += __shfl_xor(s, off, 64);
    if (lane == 0) wred[4 + q] = s;
    __syncthreads();
    s = (wred[4] + wred[5]) + (wred[6] + wred[7]);
    const float wnorm = e * (1.0f / s);
    sc[t] = wnorm;
    if (sq == 0 && t < SN) weight_out[b * SN + t] = wnorm;
    __syncthreads();

    // pool: wave q owns r-quarter, block covers its 24-25 s rows
    const int base = sq * 24 + (sq < 4 ? sq : 4);
    const int cnt  = 24 + (sq < 4 ? 1 : 0);
    const float* src = att_feats + (size_t)b * SN * RN + (size_t)base * RN
                     + q * 256 + lane * 4;
    float4 acc = {0, 0, 0, 0};
    int i = 0;
    for (; i + 5 <= cnt; i += 5) {
#pragma unroll
        for (int j = 0; j < 5; ++j) {
            float ws = sc[base + i + j];
            float4 vv = *(const float4*)(src + (size_t)(i + j) * RN);
            acc.x = fmaf(ws, vv.x, acc.x);
            acc.y = fmaf(ws, vv.y, acc.y);
            acc.z = fmaf(ws, vv.z, acc.z);
            acc.w = fmaf(ws, vv.w, acc.w);
        }
    }
#pragma unroll
    for (; i < cnt; ++i) {
        float ws = sc[base + i];
        float4 vv = *(const float4*)(src + (size_t)i * RN);
        acc.x = fmaf(ws, vv.x, acc.x);
        acc.y = fmaf(ws, vv.y, acc.y);
        acc.z = fmaf(ws, vv.z, acc.z);
        acc.w = fmaf(ws, vv.w, acc.w);
    }
    float* dst = pool_part + ((size_t)sq * BN + b) * RN + q * 256 + lane * 4;
    *(float4*)dst = acc;
}

// ---------------- kernel 4: deterministic 8-way partial reduce ----------------
__global__ __launch_bounds__(256) void k_reduce(
    const float* __restrict__ pool_part, float* __restrict__ att_res) {
    const int e = blockIdx.x * 256 + threadIdx.x;
    float s = 0.0f;
#pragma unroll
    for (int sq = 0; sq < PSPLIT; ++sq)
        s += pool_part[(size_t)sq * BN * RN + e];
    att_res[e] = s;
}

extern "C" void kernel_launch(void* const* d_in, const int* in_sizes, int n_in,
                              void* d_out, int out_size, void* d_ws, size_t ws_size,
                              hipStream_t stream) {
    const float* att_feats   = (const float*)d_in[0];  // [B,S,R]
    const float* p_att_feats = (const float*)d_in[1];  // [B,S,H]
    const float* hidden      = (const float*)d_in[2];  // [B,R]
    const float* in_weights  = (const float*)d_in[3];  // [B,S]
    const float* h2att_w     = (const float*)d_in[4];  // [H,R]
    const float* h2att_b     = (const float*)d_in[5];  // [H]
    const float* alpha_w     = (const float*)d_in[6];  // [1,H]

    float* att_res = (float*)d_out;                    // [B,R]
    float* weight  = (float*)d_out + BN * RN;          // [B,S]
    float* partial   = (float*)d_ws;                              // [KSPLIT,B,H]  4 MB
    float* pool_part = partial + (size_t)KSPLIT * BN * HN;        // [PSPLIT,B,R]  8 MB
    float* sc_raw    = pool_part + (size_t)PSPLIT * BN * RN;      // [B,S]       200 KB

    k_gemm_partial<<<dim3(BN / 64, HN / 64, KSPLIT), 256, 0, stream>>>(
        hidden, h2att_w, partial);
    k_scores<<<dim3(BN, SSPLIT), 256, 0, stream>>>(
        partial, h2att_b, p_att_feats, in_weights, alpha_w, sc_raw);
    k_pool<<<dim3(BN, PSPLIT), 256, 0, stream>>>(
        sc_raw, att_feats, pool_part, weight);
    k_reduce<<<(BN * RN) / 256, 256, 0, stream>>>(pool_part, att_res);
}